// Round 17
// baseline (208.413 us; speedup 1.0000x reference)
//
#include <hip/hip_runtime.h>

#define NN 256
#define MM 65536
#define TBL 131072
#define TBL_MASK (TBL - 1)

__device__ __forceinline__ unsigned abit(const unsigned* Abm, int m) {
    return (Abm[m >> 5] >> (m & 31)) & 1u;
}

__device__ __forceinline__ unsigned key0b(const int* x, const unsigned* Abm, int i, int j,
                                          int m) {
    return ((unsigned)x[i] << 5) | ((unsigned)x[j] << 1) | abit(Abm, m);
}

__device__ __forceinline__ unsigned long long mix64(unsigned v) {
    unsigned long long z = (unsigned long long)v + 0x9E3779B97F4A7C15ull;
    z = (z ^ (z >> 30)) * 0xBF58476D1CE4E5B9ull;
    z = (z ^ (z >> 27)) * 0x94D049BB133111EBull;
    return z ^ (z >> 31);
}

// block 0: build adjacency bitmap in LDS, write out; blocks 1..511: zero the table region
__global__ void adj_zero(const int* __restrict__ ei, int E, unsigned* __restrict__ Abm,
                         uint4* __restrict__ zdst, unsigned nzq4) {
    int b = blockIdx.x, t = threadIdx.x;
    if (b == 0) {
        __shared__ unsigned abm_s[2048];
        for (int k = t; k < 2048; k += 256) abm_s[k] = 0u;
        __syncthreads();
        for (int e = t; e < E; e += 256) {
            int s = ei[e], d = ei[E + e];
            int m = s * NN + d;
            atomicOr(&abm_s[m >> 5], 1u << (m & 31));
        }
        __syncthreads();
        for (int k = t; k < 2048; k += 256) Abm[k] = abm_s[k];
    } else {
        uint4 z;
        z.x = z.y = z.z = z.w = 0u;
        for (unsigned q = (unsigned)(b - 1) * 256u + (unsigned)t; q < nzq4; q += 511u * 256u)
            zdst[q] = z;
    }
}

// initial-coloring key pass; zeroes histogram 0 (minpos = max(~pos), zero-init tables)
__global__ void init_key(const int* __restrict__ x, const unsigned* __restrict__ Abm,
                         unsigned* __restrict__ mp0, unsigned* __restrict__ c0,
                         int* __restrict__ hist0) {
    int m = blockIdx.x * 256 + threadIdx.x;
    hist0[m] = 0;
    int i = m >> 8, j = m & 255;
    unsigned key = key0b(x, Abm, i, j, m);
    // torch order: permutations (i != j) lexicographically, then the diagonal
    unsigned pos = (i == j) ? (unsigned)(NN * (NN - 1) + i)
                            : (unsigned)(i * (NN - 1) + (j < i ? j : j - 1));
    atomicMax(&mp0[key], ~pos);
    atomicAdd(&c0[key], 1u);
}

// one block, 512 threads: rank groups by first occurrence via O(512^2) counting
__global__ void rank0_fused(const unsigned* __restrict__ mp0, const unsigned* __restrict__ c0,
                            unsigned* __restrict__ rank0, int* __restrict__ hist) {
    __shared__ unsigned pos_s[512];
    int k = threadIdx.x;
    unsigned c = c0[k];
    pos_s[k] = c ? ~mp0[k] : 0xFFFFFFFFu;
    __syncthreads();
    if (c) {
        unsigned my = pos_s[k];
        int rk = 0;
        for (int kk = 0; kk < 512; ++kk) rk += (pos_s[kk] < my);
        rank0[k] = (unsigned)rk;
        hist[rk] = (int)c;
    }
}

// commutative 64-bit multiset hash of each row (blocks 0..255) / col (256..511)
__global__ void hash_both(const int* __restrict__ x, const unsigned* __restrict__ Abm,
                          const unsigned* __restrict__ rank0, const int* __restrict__ lab,
                          int layer, unsigned long long* __restrict__ rowhash,
                          unsigned long long* __restrict__ colhash) {
    __shared__ unsigned long long hs[256];
    int b = blockIdx.x, t = threadIdx.x;
    int i = b & 255, mode = b >> 8;
    int m = mode ? t * NN + i : i * NN + t;
    unsigned lv = (layer == 0)
                      ? rank0[key0b(x, Abm, mode ? t : i, mode ? i : t, m)]
                      : (unsigned)lab[m];
    hs[t] = mix64(lv);
    __syncthreads();
    for (int off = 128; off > 0; off >>= 1) {
        if (t < off) hs[t] += hs[t + off];
        __syncthreads();
    }
    if (t == 0) (mode ? colhash : rowhash)[i] = hs[0];
}

// per-block redundant rep computation (block's own rvec + full cvec) + hash-table insert
__global__ void insert_rep(const int* __restrict__ x, const unsigned* __restrict__ Abm,
                           const unsigned* __restrict__ rank0, const int* __restrict__ lab,
                           int layer, const unsigned long long* __restrict__ rowhash,
                           const unsigned long long* __restrict__ colhash,
                           unsigned long long* __restrict__ tk, unsigned* __restrict__ mp,
                           unsigned* __restrict__ cnt, unsigned* __restrict__ slotidx) {
    __shared__ unsigned long long rh[256];
    __shared__ unsigned long long ch[256];
    __shared__ int cvec_s[256];
    __shared__ int rvec_b;
    int b = blockIdx.x, t = threadIdx.x;
    rh[t] = rowhash[t];
    ch[t] = colhash[t];
    __syncthreads();
    // cvec_s[t] = min j with ch[j] == ch[t]
    {
        unsigned long long my = ch[t];
        int r = t;
        for (int j = 0; j < t; ++j) {
            if (ch[j] == my) {
                r = j;
                break;
            }
        }
        cvec_s[t] = r;
    }
    if (t == 0) {
        unsigned long long my = rh[b];
        int r = b;
        for (int j = 0; j < b; ++j) {
            if (rh[j] == my) {
                r = j;
                break;
            }
        }
        rvec_b = r;
    }
    __syncthreads();

    int m = b * 256 + t;  // i = b, j = t
    unsigned l = (layer == 0) ? rank0[key0b(x, Abm, b, t, m)] : (unsigned)lab[m];
    unsigned key = l | ((unsigned)rvec_b << 16) | ((unsigned)cvec_s[t] << 24);
    unsigned long long kk = (unsigned long long)key + 1ull;  // 0 = empty
    unsigned h = ((key * 2654435761u) >> 15) & TBL_MASK;
    for (;;) {
        unsigned long long prev = atomicCAS(&tk[h], 0ull, kk);
        if (prev == 0ull || prev == kk) break;
        h = (h + 1) & TBL_MASK;
    }
    slotidx[m] = h;
    atomicMax(&mp[h], ~(unsigned)m);  // encoded min-pos, zero-init
    atomicAdd(&cnt[h], 1u);
}

// set first-occurrence bits in a 2048-word bitmap; zero this layer's histogram
__global__ void mark_bm(const unsigned long long* __restrict__ tk,
                        const unsigned* __restrict__ mp, unsigned* __restrict__ bm,
                        int* __restrict__ hist) {
    int s = blockIdx.x * 256 + threadIdx.x;  // spans TBL
    if (s < MM) hist[s] = 0;
    if (tk[s]) {
        unsigned q = ~mp[s];
        atomicOr(&bm[q >> 5], 1u << (q & 31));
    }
}

// per-block redundant prefix-popcount of the bitmap -> rank(); write labels + histogram
__global__ void finish_bm(const unsigned long long* __restrict__ tk,
                          const unsigned* __restrict__ mp, const unsigned* __restrict__ cnt,
                          const unsigned* __restrict__ bm, const unsigned* __restrict__ slotidx,
                          int* __restrict__ hist, int* __restrict__ lab) {
    __shared__ unsigned bw[2048];  // bitmap words
    __shared__ unsigned wb[2048];  // per-word exclusive popcount base
    __shared__ unsigned ts[256];   // per-thread sums
    int t = threadIdx.x;
    for (int k = t; k < 2048; k += 256) bw[k] = bm[k];
    __syncthreads();
    unsigned pc[8], s = 0;
#pragma unroll
    for (int k = 0; k < 8; ++k) {
        pc[k] = (unsigned)__popc(bw[t * 8 + k]);
        s += pc[k];
    }
    ts[t] = s;
    __syncthreads();
    for (int off = 1; off < 256; off <<= 1) {
        unsigned v = (t >= off) ? ts[t - off] : 0u;
        __syncthreads();
        ts[t] += v;
        __syncthreads();
    }
    unsigned run = ts[t] - s;  // exclusive base for this thread's 8 words
#pragma unroll
    for (int k = 0; k < 8; ++k) {
        wb[t * 8 + k] = run;
        run += pc[k];
    }
    __syncthreads();

    int sdx = blockIdx.x * 256 + t;  // spans TBL
    if (sdx < MM) {
        unsigned q = ~mp[slotidx[sdx]];
        lab[sdx] = (int)(wb[q >> 5] + (unsigned)__popc(bw[q >> 5] & ((1u << (q & 31)) - 1u)));
    }
    if (tk[sdx]) {
        unsigned q = ~mp[sdx];
        unsigned rk = wb[q >> 5] + (unsigned)__popc(bw[q >> 5] & ((1u << (q & 31)) - 1u));
        hist[rk] = (int)cnt[sdx];
    }
}

extern "C" void kernel_launch(void* const* d_in, const int* in_sizes, int n_in,
                              void* d_out, int out_size, void* d_ws, size_t ws_size,
                              hipStream_t stream) {
    const int* x = (const int*)d_in[0];
    const int* ei = (const int*)d_in[1];
    const int E = in_sizes[1] / 2;
    int* out = (int*)d_out;  // int32 histograms

    // ---- workspace carve-up (512B aligned) ----
    char* w = (char*)d_ws;
    size_t off = 0;
    auto alloc = [&](size_t bytes) -> void* {
        void* p = w + off;
        off = (off + bytes + 511) & ~(size_t)511;
        return p;
    };
    // Abm first (zeroed in-kernel by block 0), then the zero region for blocks 1..511
    unsigned* Abm = (unsigned*)alloc(2048 * 4);
    size_t zero_begin = off;
    unsigned long long* tkL[2] = {(unsigned long long*)alloc(TBL * 8),
                                  (unsigned long long*)alloc(TBL * 8)};
    unsigned* mpL[2] = {(unsigned*)alloc(TBL * 4), (unsigned*)alloc(TBL * 4)};
    unsigned* cntL[2] = {(unsigned*)alloc(TBL * 4), (unsigned*)alloc(TBL * 4)};
    unsigned* bmL[2] = {(unsigned*)alloc(2048 * 4), (unsigned*)alloc(2048 * 4)};
    unsigned* mp0 = (unsigned*)alloc(512 * 4);
    unsigned* c0 = (unsigned*)alloc(512 * 4);
    size_t zero_end = off;
    // non-zeroed scratch (fully written before read, every launch)
    unsigned* slotidx = (unsigned*)alloc(MM * 4);
    int* lab = (int*)alloc(MM * 4);
    unsigned long long* rowhash = (unsigned long long*)alloc(NN * 8);
    unsigned long long* colhash = (unsigned long long*)alloc(NN * 8);
    unsigned* rank0 = (unsigned*)alloc(512 * 4);

    unsigned nzq4 = (unsigned)((zero_end - zero_begin) / 16);

    adj_zero<<<512, 256, 0, stream>>>(ei, E, Abm, (uint4*)(w + zero_begin), nzq4);
    init_key<<<MM / 256, 256, 0, stream>>>(x, Abm, mp0, c0, out);
    rank0_fused<<<1, 512, 0, stream>>>(mp0, c0, rank0, out);

    for (int layer = 0; layer < 2; ++layer) {
        int* hist = out + (size_t)(layer + 1) * MM;
        hash_both<<<2 * NN, NN, 0, stream>>>(x, Abm, rank0, lab, layer, rowhash, colhash);
        insert_rep<<<MM / 256, 256, 0, stream>>>(x, Abm, rank0, lab, layer, rowhash, colhash,
                                                 tkL[layer], mpL[layer], cntL[layer], slotidx);
        mark_bm<<<TBL / 256, 256, 0, stream>>>(tkL[layer], mpL[layer], bmL[layer], hist);
        finish_bm<<<TBL / 256, 256, 0, stream>>>(tkL[layer], mpL[layer], cntL[layer], bmL[layer],
                                                 slotidx, hist, lab);
    }
}

// Round 19
// 174.187 us; speedup vs baseline: 1.1965x; 1.1965x over previous
//
#include <hip/hip_runtime.h>

#define NN 256
#define MM 65536
#define TBL 131072
#define TBL_MASK (TBL - 1)

__device__ __forceinline__ unsigned abit(const unsigned* Abm, int m) {
    return (Abm[m >> 5] >> (m & 31)) & 1u;
}

__device__ __forceinline__ unsigned key0b(const int* x, const unsigned* Abm, int i, int j,
                                          int m) {
    return ((unsigned)x[i] << 5) | ((unsigned)x[j] << 1) | abit(Abm, m);
}

__device__ __forceinline__ unsigned long long mix64(unsigned v) {
    unsigned long long z = (unsigned long long)v + 0x9E3779B97F4A7C15ull;
    z = (z ^ (z >> 30)) * 0xBF58476D1CE4E5B9ull;
    z = (z ^ (z >> 27)) * 0x94D049BB133111EBull;
    return z ^ (z >> 31);
}

// block 0: build adjacency bitmap in LDS, write out; blocks 1..511: zero the table region
__global__ void adj_zero(const int* __restrict__ ei, int E, unsigned* __restrict__ Abm,
                         uint4* __restrict__ zdst, unsigned nzq4) {
    int b = blockIdx.x, t = threadIdx.x;
    if (b == 0) {
        __shared__ unsigned abm_s[2048];
        for (int k = t; k < 2048; k += 256) abm_s[k] = 0u;
        __syncthreads();
        for (int e = t; e < E; e += 256) {
            int s = ei[e], d = ei[E + e];
            int m = s * NN + d;
            atomicOr(&abm_s[m >> 5], 1u << (m & 31));
        }
        __syncthreads();
        for (int k = t; k < 2048; k += 256) Abm[k] = abm_s[k];
    } else {
        uint4 z;
        z.x = z.y = z.z = z.w = 0u;
        for (unsigned q = (unsigned)(b - 1) * 256u + (unsigned)t; q < nzq4; q += 511u * 256u)
            zdst[q] = z;
    }
}

// initial-coloring key pass; zeroes histogram 0 (minpos = max(~pos), zero-init tables)
__global__ void init_key(const int* __restrict__ x, const unsigned* __restrict__ Abm,
                         unsigned* __restrict__ mp0, unsigned* __restrict__ c0,
                         int* __restrict__ hist0) {
    int m = blockIdx.x * 256 + threadIdx.x;
    hist0[m] = 0;
    int i = m >> 8, j = m & 255;
    unsigned key = key0b(x, Abm, i, j, m);
    // torch order: permutations (i != j) lexicographically, then the diagonal
    unsigned pos = (i == j) ? (unsigned)(NN * (NN - 1) + i)
                            : (unsigned)(i * (NN - 1) + (j < i ? j : j - 1));
    atomicMax(&mp0[key], ~pos);
    atomicAdd(&c0[key], 1u);
}

// one block, 512 threads: rank groups by first occurrence via O(512^2) counting
__global__ void rank0_fused(const unsigned* __restrict__ mp0, const unsigned* __restrict__ c0,
                            unsigned* __restrict__ rank0, int* __restrict__ hist) {
    __shared__ unsigned pos_s[512];
    int k = threadIdx.x;
    unsigned c = c0[k];
    pos_s[k] = c ? ~mp0[k] : 0xFFFFFFFFu;
    __syncthreads();
    if (c) {
        unsigned my = pos_s[k];
        int rk = 0;
        for (int kk = 0; kk < 512; ++kk) rk += (pos_s[kk] < my);
        rank0[k] = (unsigned)rk;
        hist[rk] = (int)c;
    }
}

// commutative 64-bit multiset hash of each row (blocks 0..255) / col (256..511)
__global__ void hash_both(const int* __restrict__ x, const unsigned* __restrict__ Abm,
                          const unsigned* __restrict__ rank0, const int* __restrict__ lab,
                          int layer, unsigned long long* __restrict__ rowhash,
                          unsigned long long* __restrict__ colhash) {
    __shared__ unsigned long long hs[256];
    int b = blockIdx.x, t = threadIdx.x;
    int i = b & 255, mode = b >> 8;
    int m = mode ? t * NN + i : i * NN + t;
    unsigned lv = (layer == 0)
                      ? rank0[key0b(x, Abm, mode ? t : i, mode ? i : t, m)]
                      : (unsigned)lab[m];
    hs[t] = mix64(lv);
    __syncthreads();
    for (int off = 128; off > 0; off >>= 1) {
        if (t < off) hs[t] += hs[t + off];
        __syncthreads();
    }
    if (t == 0) (mode ? colhash : rowhash)[i] = hs[0];
}

// rep computation (parallel, branch-free) + hash-table insert
__global__ void insert_rep(const int* __restrict__ x, const unsigned* __restrict__ Abm,
                           const unsigned* __restrict__ rank0, const int* __restrict__ lab,
                           int layer, const unsigned long long* __restrict__ rowhash,
                           const unsigned long long* __restrict__ colhash,
                           unsigned long long* __restrict__ tk, unsigned* __restrict__ mp,
                           unsigned* __restrict__ cnt, unsigned* __restrict__ slotidx) {
    __shared__ unsigned long long rh[256];
    __shared__ unsigned long long ch[256];
    __shared__ int rvb;
    int b = blockIdx.x, t = threadIdx.x;
    rh[t] = rowhash[t];
    ch[t] = colhash[t];
    if (t == 0) rvb = b;
    __syncthreads();
    // row rep of this block: one LDS atomicMin per matching thread (no serial chain)
    if (t < b && rh[t] == rh[b]) atomicMin(&rvb, t);
    // col rep of this thread: branch-free ascending scan, unconditional broadcast reads
    unsigned long long my = ch[t];
    int r = t;
#pragma unroll 16
    for (int j = 0; j < 256; ++j) {
        unsigned long long v = ch[j];
        r = (v == my && j < r) ? j : r;
    }
    __syncthreads();  // rvb final

    int m = b * 256 + t;  // i = b, j = t
    unsigned l = (layer == 0) ? rank0[key0b(x, Abm, b, t, m)] : (unsigned)lab[m];
    unsigned key = l | ((unsigned)rvb << 16) | ((unsigned)r << 24);
    unsigned long long kk = (unsigned long long)key + 1ull;  // 0 = empty
    unsigned h = ((key * 2654435761u) >> 15) & TBL_MASK;
    for (;;) {
        unsigned long long prev = atomicCAS(&tk[h], 0ull, kk);
        if (prev == 0ull || prev == kk) break;
        h = (h + 1) & TBL_MASK;
    }
    slotidx[m] = h;
    atomicMax(&mp[h], ~(unsigned)m);  // encoded min-pos, zero-init
    atomicAdd(&cnt[h], 1u);
}

// set first-occurrence bits in a 2048-word bitmap; zero this layer's histogram
__global__ void mark_bm(const unsigned long long* __restrict__ tk,
                        const unsigned* __restrict__ mp, unsigned* __restrict__ bm,
                        int* __restrict__ hist) {
    int s = blockIdx.x * 256 + threadIdx.x;  // spans TBL
    if (s < MM) hist[s] = 0;
    if (tk[s]) {
        unsigned q = ~mp[s];
        atomicOr(&bm[q >> 5], 1u << (q & 31));
    }
}

// per-block redundant prefix-popcount of the bitmap -> rank(); write labels + histogram
__global__ void finish_bm(const unsigned long long* __restrict__ tk,
                          const unsigned* __restrict__ mp, const unsigned* __restrict__ cnt,
                          const unsigned* __restrict__ bm, const unsigned* __restrict__ slotidx,
                          int* __restrict__ hist, int* __restrict__ lab) {
    __shared__ unsigned bw[2048];  // bitmap words
    __shared__ unsigned wb[2048];  // per-word exclusive popcount base
    __shared__ unsigned ts[256];   // per-thread sums
    int t = threadIdx.x;
    for (int k = t; k < 2048; k += 256) bw[k] = bm[k];
    __syncthreads();
    unsigned pc[8], s = 0;
#pragma unroll
    for (int k = 0; k < 8; ++k) {
        pc[k] = (unsigned)__popc(bw[t * 8 + k]);
        s += pc[k];
    }
    ts[t] = s;
    __syncthreads();
    for (int off = 1; off < 256; off <<= 1) {
        unsigned v = (t >= off) ? ts[t - off] : 0u;
        __syncthreads();
        ts[t] += v;
        __syncthreads();
    }
    unsigned run = ts[t] - s;  // exclusive base for this thread's 8 words
#pragma unroll
    for (int k = 0; k < 8; ++k) {
        wb[t * 8 + k] = run;
        run += pc[k];
    }
    __syncthreads();

    int sdx = blockIdx.x * 256 + t;  // spans TBL
    if (sdx < MM) {
        unsigned q = ~mp[slotidx[sdx]];
        lab[sdx] = (int)(wb[q >> 5] + (unsigned)__popc(bw[q >> 5] & ((1u << (q & 31)) - 1u)));
    }
    if (tk[sdx]) {
        unsigned q = ~mp[sdx];
        unsigned rk = wb[q >> 5] + (unsigned)__popc(bw[q >> 5] & ((1u << (q & 31)) - 1u));
        hist[rk] = (int)cnt[sdx];
    }
}

extern "C" void kernel_launch(void* const* d_in, const int* in_sizes, int n_in,
                              void* d_out, int out_size, void* d_ws, size_t ws_size,
                              hipStream_t stream) {
    const int* x = (const int*)d_in[0];
    const int* ei = (const int*)d_in[1];
    const int E = in_sizes[1] / 2;
    int* out = (int*)d_out;  // int32 histograms

    // ---- workspace carve-up (512B aligned) ----
    char* w = (char*)d_ws;
    size_t off = 0;
    auto alloc = [&](size_t bytes) -> void* {
        void* p = w + off;
        off = (off + bytes + 511) & ~(size_t)511;
        return p;
    };
    // Abm first (zeroed in-kernel by block 0), then the zero region for blocks 1..511
    unsigned* Abm = (unsigned*)alloc(2048 * 4);
    size_t zero_begin = off;
    unsigned long long* tkL[2] = {(unsigned long long*)alloc(TBL * 8),
                                  (unsigned long long*)alloc(TBL * 8)};
    unsigned* mpL[2] = {(unsigned*)alloc(TBL * 4), (unsigned*)alloc(TBL * 4)};
    unsigned* cntL[2] = {(unsigned*)alloc(TBL * 4), (unsigned*)alloc(TBL * 4)};
    unsigned* bmL[2] = {(unsigned*)alloc(2048 * 4), (unsigned*)alloc(2048 * 4)};
    unsigned* mp0 = (unsigned*)alloc(512 * 4);
    unsigned* c0 = (unsigned*)alloc(512 * 4);
    size_t zero_end = off;
    // non-zeroed scratch (fully written before read, every launch)
    unsigned* slotidx = (unsigned*)alloc(MM * 4);
    int* lab = (int*)alloc(MM * 4);
    unsigned long long* rowhash = (unsigned long long*)alloc(NN * 8);
    unsigned long long* colhash = (unsigned long long*)alloc(NN * 8);
    unsigned* rank0 = (unsigned*)alloc(512 * 4);

    unsigned nzq4 = (unsigned)((zero_end - zero_begin) / 16);

    adj_zero<<<512, 256, 0, stream>>>(ei, E, Abm, (uint4*)(w + zero_begin), nzq4);
    init_key<<<MM / 256, 256, 0, stream>>>(x, Abm, mp0, c0, out);
    rank0_fused<<<1, 512, 0, stream>>>(mp0, c0, rank0, out);

    for (int layer = 0; layer < 2; ++layer) {
        int* hist = out + (size_t)(layer + 1) * MM;
        hash_both<<<2 * NN, NN, 0, stream>>>(x, Abm, rank0, lab, layer, rowhash, colhash);
        insert_rep<<<MM / 256, 256, 0, stream>>>(x, Abm, rank0, lab, layer, rowhash, colhash,
                                                 tkL[layer], mpL[layer], cntL[layer], slotidx);
        mark_bm<<<TBL / 256, 256, 0, stream>>>(tkL[layer], mpL[layer], bmL[layer], hist);
        finish_bm<<<TBL / 256, 256, 0, stream>>>(tkL[layer], mpL[layer], cntL[layer], bmL[layer],
                                                 slotidx, hist, lab);
    }
}